// Round 2
// 649.377 us; speedup vs baseline: 1.3589x; 1.3589x over previous
//
#include <hip/hip_runtime.h>

// LSPD_43404939493531: bidirectional 2-layer GRU (B=512,T=512,U=32) + BN folds + dense head.
// R7: R6 retry. R6's wrong-result root cause: inline-asm permlane*_swap with two "+v" operands
//     whose inputs were COPIES OF THE SAME VALUE -> regalloc coalesced both operands into ONE
//     VGPR, emitting "v_permlane16_swap_b32 v5, v5" (self-swap scrambles rows in-place; both
//     selected halves became identical, k-coverage broke, absmax 0.796). Fix: use the gfx950
//     two-result builtins __builtin_amdgcn_permlane{16,32}_swap (compiler models vdst/vsrc pair,
//     cannot coalesce; DPP hazards compiler-managed). Fallback asm forces distinct regs via
//     explicit v_mov + earlyclobber and adds s_nop for the VALU->DPP wait-state hazard.
//     Rest identical to R6: all cross-lane ops on the VALU pipe (permlane swap + 16x DPP
//     row_newbcast + permlane32 half-sum), coefficient arrays preloaded through the SAME lane
//     permutation applied to the channel index (kk[j]) so hk[j]==h[kk[j]] by construction,
//     4-deep register-rotated prefetch for gru1 x-stream / gru0 tab-gathers (idx 8 ahead).

#define Bsz 512
#define Tsz 512

typedef unsigned uintv2 __attribute__((ext_vector_type(2)));

__device__ __forceinline__ float sigmoid_f(float x) {
    return __builtin_amdgcn_rcpf(1.0f + __expf(-x));
}

// ---- cross-lane primitives: VALU pipe only, no LDS ----
__device__ __forceinline__ void plswap16_f(float& a, float& b) {
#if __has_builtin(__builtin_amdgcn_permlane16_swap)
    uintv2 r = __builtin_amdgcn_permlane16_swap(__float_as_uint(a), __float_as_uint(b), false, false);
    a = __uint_as_float(r.x);
    b = __uint_as_float(r.y);
#else
    asm("v_mov_b32 %1, %0\n\t"
        "v_permlane16_swap_b32 %0, %1\n\t"
        "s_nop 1"
        : "+v"(a), "=&v"(b));
#endif
}
__device__ __forceinline__ void plswap16_i(int& a, int& b) {
#if __has_builtin(__builtin_amdgcn_permlane16_swap)
    uintv2 r = __builtin_amdgcn_permlane16_swap((unsigned)a, (unsigned)b, false, false);
    a = (int)r.x;
    b = (int)r.y;
#else
    asm("v_mov_b32 %1, %0\n\t"
        "v_permlane16_swap_b32 %0, %1\n\t"
        "s_nop 1"
        : "+v"(a), "=&v"(b));
#endif
}
__device__ __forceinline__ float xhalfsum(float a) {   // a[lane] + a[lane^32]
#if __has_builtin(__builtin_amdgcn_permlane32_swap)
    uintv2 r = __builtin_amdgcn_permlane32_swap(__float_as_uint(a), __float_as_uint(a), false, false);
    return __uint_as_float(r.x) + __uint_as_float(r.y);
#else
    float b;
    asm("v_mov_b32 %1, %0\n\t"
        "v_permlane32_swap_b32 %0, %1\n\t"
        "s_nop 1"
        : "+v"(a), "=&v"(b));
    return a + b;
#endif
}

// DPP row_newbcast:n (ctrl 0x150+n): broadcast in-row lane n to the whole 16-lane row
#define NB_F(d, s, n) d = __int_as_float(__builtin_amdgcn_update_dpp(0, __float_as_int(s), 0x150 + n, 0xF, 0xF, true))
#define NB_I(d, s, n) d = __builtin_amdgcn_update_dpp(0, (s), 0x150 + n, 0xF, 0xF, true)
#define BCAST16F(A, S)                                                         \
    NB_F(A[0], S, 0);  NB_F(A[1], S, 1);  NB_F(A[2], S, 2);  NB_F(A[3], S, 3); \
    NB_F(A[4], S, 4);  NB_F(A[5], S, 5);  NB_F(A[6], S, 6);  NB_F(A[7], S, 7); \
    NB_F(A[8], S, 8);  NB_F(A[9], S, 9);  NB_F(A[10], S, 10); NB_F(A[11], S, 11); \
    NB_F(A[12], S, 12); NB_F(A[13], S, 13); NB_F(A[14], S, 14); NB_F(A[15], S, 15)
#define BCAST16I(A, S)                                                         \
    NB_I(A[0], S, 0);  NB_I(A[1], S, 1);  NB_I(A[2], S, 2);  NB_I(A[3], S, 3); \
    NB_I(A[4], S, 4);  NB_I(A[5], S, 5);  NB_I(A[6], S, 6);  NB_I(A[7], S, 7); \
    NB_I(A[8], S, 8);  NB_I(A[9], S, 9);  NB_I(A[10], S, 10); NB_I(A[11], S, 11); \
    NB_I(A[12], S, 12); NB_I(A[13], S, 13); NB_I(A[14], S, 14); NB_I(A[15], S, 15)

// ---------------- K1: argmax over D=128, one wave per (b,t), t-fastest ----------------
__global__ __launch_bounds__(256) void lspd_argmax(const float* __restrict__ x, int* __restrict__ idxT)
{
    int wv = threadIdx.x >> 6, lane = threadIdx.x & 63;
    long p = (long)blockIdx.x * 4 + wv;           // p = b*512 + t
    const float* xp = x + p * 128;
    float v0 = xp[lane];      int i0 = lane;
    float v1 = xp[64 + lane]; int i1 = 64 + lane;
    if (v1 > v0) { v0 = v1; i0 = i1; }            // ties keep lower index (first occurrence)
#pragma unroll
    for (int d = 1; d < 64; d <<= 1) {
        float ov = __shfl_xor(v0, d, 64);
        int   oi = __shfl_xor(i0, d, 64);
        if (ov > v0 || (ov == v0 && oi < i0)) { v0 = ov; i0 = oi; }
    }
    if (lane == 0) idxT[p] = i0;
}

// ---------------- K0: layer-0 input tables tab[i][g] = (emb@W0)[i][g] + b0_in[g] ----------------
__global__ __launch_bounds__(256) void lspd_tab(
    const float* __restrict__ emb, const float* __restrict__ Wl, const float* __restrict__ bl,
    const float* __restrict__ Wr, const float* __restrict__ br,
    float* __restrict__ tabL, float* __restrict__ tabR)
{
    int flat = blockIdx.x * 256 + threadIdx.x;    // 0..24575
    int dir = flat / 12288;
    int r = flat % 12288;
    int i = r / 96, g = r % 96;
    const float* W  = dir ? Wr : Wl;              // layer 0 at base
    const float* bb = dir ? br : bl;              // b[0][0] input bias at base
    float acc = bb[g];
#pragma unroll
    for (int k = 0; k < 32; ++k) acc = fmaf(emb[i * 32 + k], W[k * 96 + g], acc);
    (dir ? tabR : tabL)[r] = acc;
}

// ---------------- K2: layer-0 GRU, 1 row per wave64, both directions in one grid ----------------
__global__ __launch_bounds__(64)
__attribute__((amdgpu_waves_per_eu(1, 1)))
void lspd_gru0(
    const int* __restrict__ idxT, const float* __restrict__ tabL, const float* __restrict__ tabR,
    const float* __restrict__ Ul, const float* __restrict__ Ur,
    const float* __restrict__ bl, const float* __restrict__ br,
    float* __restrict__ Lout, float* __restrict__ Rout)
{
    int wid = blockIdx.x;
    int dir = wid >> 9;
    int b = wid & 511;
    int lane = threadIdx.x;
    int half = lane >> 5, c = lane & 31;
    const float* U    = dir ? Ur : Ul;
    const float* tab  = dir ? tabR : tabL;
    const float* brec = (dir ? br : bl) + 96;     // layer-0 recurrent bias b[0][1]
    float* out        = dir ? Rout : Lout;

    // ---- permutation self-calibration: kk[j] = channel whose h lands in hk[j] ----
    int ksA = c, ksB = c;
    plswap16_i(ksA, ksB);
    bool selA = ((ksA >> 4) == half);
    int ksel = selA ? ksA : ksB;
    int kk[16];
    BCAST16I(kk, ksel);

    float u0[16], u1[16], u2[16];
#pragma unroll
    for (int j = 0; j < 16; ++j) {
        u0[j] = U[kk[j] * 96 + c];
        u1[j] = U[kk[j] * 96 + 32 + c];
        u2[j] = U[kk[j] * 96 + 64 + c];
    }
    float bZ = half ? 0.f : brec[c];
    float bR = half ? 0.f : brec[32 + c];
    float bH = half ? 0.f : brec[64 + c];
#pragma unroll
    for (int j = 0; j < 16; ++j) {
        asm volatile("" : "+v"(u0[j]), "+v"(u1[j]), "+v"(u2[j]));
    }
    asm volatile("" : "+v"(bZ), "+v"(bR), "+v"(bH));

    const int* idxrow = idxT + (long)b * Tsz;
    if (lane < 32) out[(((long)(dir ? Tsz - 1 : 0)) * Bsz + b) * 32 + c] = 0.f;  // boundary zero

#define TT0(s) (dir ? (Tsz - 2 - (s)) : (1 + (s)))
    long ob = ((long)TT0(0) * Bsz + b) * 32 + c;
    long ostride = (long)(dir ? -1 : 1) * Bsz * 32;

    // 4-slot gi pipeline (gather 4 steps ahead), idx 8 steps ahead
    float g0z, g0r, g0h, g1z, g1r, g1h, g2z, g2r, g2h, g3z, g3r, g3h;
    { int i = idxrow[TT0(0)]; g0z = tab[i * 96 + c]; g0r = tab[i * 96 + 32 + c]; g0h = tab[i * 96 + 64 + c]; }
    { int i = idxrow[TT0(1)]; g1z = tab[i * 96 + c]; g1r = tab[i * 96 + 32 + c]; g1h = tab[i * 96 + 64 + c]; }
    { int i = idxrow[TT0(2)]; g2z = tab[i * 96 + c]; g2r = tab[i * 96 + 32 + c]; g2h = tab[i * 96 + 64 + c]; }
    { int i = idxrow[TT0(3)]; g3z = tab[i * 96 + c]; g3r = tab[i * 96 + 32 + c]; g3h = tab[i * 96 + 64 + c]; }
    int i0 = idxrow[TT0(4)];
    int i1 = idxrow[TT0(5)];
    int i2 = idxrow[TT0(6)];
    int i3 = idxrow[TT0(7)];
    float h = 0.f;

#define GSTEP(GZ, GR, GH, IREG, SNEXT)                                         \
    {                                                                          \
        float ha = h, hb = h;                                                  \
        plswap16_f(ha, hb);                                                    \
        float hs = selA ? ha : hb;                                             \
        float hk[16];                                                          \
        BCAST16F(hk, hs);                                                      \
        float az = bZ, ar = bR, ah = bH;                                       \
        _Pragma("unroll")                                                      \
        for (int n = 0; n < 16; ++n) {                                         \
            az = fmaf(hk[n], u0[n], az);                                       \
            ar = fmaf(hk[n], u1[n], ar);                                       \
            ah = fmaf(hk[n], u2[n], ah);                                       \
        }                                                                      \
        az = xhalfsum(az); ar = xhalfsum(ar); ah = xhalfsum(ah);               \
        float z = sigmoid_f(az + GZ);                                          \
        float r = sigmoid_f(ar + GR);                                          \
        float hh = fmaxf(0.f, fmaf(r, ah, GH));                                \
        h = hh + z * (h - hh);                                                 \
        if (lane < 32) out[ob] = h;                                            \
        ob += ostride;                                                         \
        GZ = tab[IREG * 96 + c];                                               \
        GR = tab[IREG * 96 + 32 + c];                                          \
        GH = tab[IREG * 96 + 64 + c];                                          \
        IREG = idxrow[TT0(SNEXT)];                                             \
    }

    for (int sb = 0; sb < 508; sb += 4) {
        int s8 = sb + 8;  if (s8  > 510) s8  = 510;
        int s9 = sb + 9;  if (s9  > 510) s9  = 510;
        int s10 = sb + 10; if (s10 > 510) s10 = 510;
        int s11 = sb + 11; if (s11 > 510) s11 = 510;
        GSTEP(g0z, g0r, g0h, i0, s8);
        GSTEP(g1z, g1r, g1h, i1, s9);
        GSTEP(g2z, g2r, g2h, i2, s10);
        GSTEP(g3z, g3r, g3h, i3, s11);
    }
    // tail: steps 508, 509, 510 (refills are clamped duplicates, dead)
    GSTEP(g0z, g0r, g0h, i0, 510);
    GSTEP(g1z, g1r, g1h, i1, 510);
    GSTEP(g2z, g2r, g2h, i2, 510);
#undef GSTEP
#undef TT0
}

// ---------------- K3/K5: per-channel sum & sumsq of (L+R) ----------------
__global__ __launch_bounds__(256) void lspd_stats(
    const float* __restrict__ A, const float* __restrict__ Bv, float* __restrict__ part)
{
    __shared__ float sS[256], sQ[256];
    int tid = threadIdx.x;
    size_t base = (size_t)blockIdx.x * 65536 + tid;
    float s = 0.f, q = 0.f;
    for (int i = 0; i < 256; ++i) {
        size_t ix = base + (size_t)i * 256;
        float v = A[ix] + Bv[ix];
        s += v; q = fmaf(v, v, q);
    }
    sS[tid] = s; sQ[tid] = q;
    __syncthreads();
    if (tid < 32) {
        float S = 0.f, Q = 0.f;
        for (int j = 0; j < 8; ++j) { S += sS[tid + 32 * j]; Q += sQ[tid + 32 * j]; }
        part[blockIdx.x * 64 + tid] = S;
        part[blockIdx.x * 64 + 32 + tid] = Q;
    }
}

// ---------------- K3b: fold layer-0 BN into layer-1 input weights ----------------
__global__ __launch_bounds__(256) void lspd_fold1(
    const float* __restrict__ part, const float* __restrict__ g0, const float* __restrict__ be0,
    const float* __restrict__ Wl, const float* __restrict__ Wr,
    const float* __restrict__ bl, const float* __restrict__ br,
    float* __restrict__ WpL, float* __restrict__ WpR,
    float* __restrict__ b4L, float* __restrict__ b4R)
{
    __shared__ float sc[32], tc[32];
    int tid = threadIdx.x;
    if (tid < 32) {
        float S = 0.f, Q = 0.f;
        for (int p = 0; p < 128; ++p) { S += part[p * 64 + tid]; Q += part[p * 64 + 32 + tid]; }
        const float invN = 1.0f / 262144.0f;
        float m = S * invN;
        float v = Q * invN - m * m;
        float s = g0[tid] * __builtin_amdgcn_rsqf(v + 1e-3f);
        sc[tid] = s; tc[tid] = be0[tid] - s * m;
    }
    __syncthreads();
    for (int idx = tid; idx < 6144; idx += 256) {
        int dir = idx / 3072, e = idx % 3072, k = e / 96, g = e % 96;
        const float* W1 = (dir ? Wr : Wl) + 3072;      // layer 1
        (dir ? WpR : WpL)[e] = sc[k] * W1[k * 96 + g];
    }
    {
        int idx = tid;                                  // 256 entries exactly
        int dir = idx >> 7, slot = idx & 127, sub = slot >> 5, cc = slot & 31;
        const float* bb = (dir ? br : bl) + 192;        // layer-1: [0..95]=input, [96..191]=recurrent
        const float* W1 = (dir ? Wr : Wl) + 3072;
        float r;
        if (sub == 2) {
            r = bb[96 + 64 + cc];                       // rh: recurrent h-bias only
        } else {
            int g = (sub == 3) ? (64 + cc) : (sub * 32 + cc);
            float acc = bb[g];                          // input bias
            for (int k = 0; k < 32; ++k) acc = fmaf(tc[k], W1[k * 96 + g], acc);
            if (sub < 2) acc += bb[96 + g];             // z,r: + recurrent bias
            r = acc;
        }
        (dir ? b4R : b4L)[slot] = r;
    }
}

// ---------------- K4: layer-1 GRU with on-the-fly folded input projection ----------------
__global__ __launch_bounds__(64)
__attribute__((amdgpu_waves_per_eu(1, 1)))
void lspd_gru1(
    const float* __restrict__ L0, const float* __restrict__ R0,
    const float* __restrict__ WpL, const float* __restrict__ WpR,
    const float* __restrict__ b4L, const float* __restrict__ b4R,
    const float* __restrict__ Ul1, const float* __restrict__ Ur1,
    float* __restrict__ Lout, float* __restrict__ Rout)
{
    int wid = blockIdx.x;
    int dir = wid >> 9;
    int b = wid & 511;
    int lane = threadIdx.x;
    int half = lane >> 5, c = lane & 31;
    const float* U  = dir ? Ur1 : Ul1;
    const float* Wp = dir ? WpR : WpL;
    const float* b4 = dir ? b4R : b4L;
    float* out      = dir ? Rout : Lout;

    // ---- permutation self-calibration (same ops as runtime path) ----
    int ksA = c, ksB = c;
    plswap16_i(ksA, ksB);
    bool selA = ((ksA >> 4) == half);
    int ksel = selA ? ksA : ksB;
    int kk[16];
    BCAST16I(kk, ksel);

    float u0[16], u1[16], u2[16], w0[16], w1[16], w2[16];
#pragma unroll
    for (int j = 0; j < 16; ++j) {
        u0[j] = U[kk[j] * 96 + c];
        u1[j] = U[kk[j] * 96 + 32 + c];
        u2[j] = U[kk[j] * 96 + 64 + c];
        w0[j] = Wp[kk[j] * 96 + c];
        w1[j] = Wp[kk[j] * 96 + 32 + c];
        w2[j] = Wp[kk[j] * 96 + 64 + c];
    }
    float bZ = half ? 0.f : b4[c];
    float bR = half ? 0.f : b4[32 + c];
    float bH = half ? 0.f : b4[64 + c];   // recurrent-h bias
    float bI = half ? 0.f : b4[96 + c];   // input-h bias (folded)
#pragma unroll
    for (int j = 0; j < 16; ++j) {
        asm volatile("" : "+v"(u0[j]), "+v"(u1[j]), "+v"(u2[j]));
        asm volatile("" : "+v"(w0[j]), "+v"(w1[j]), "+v"(w2[j]));
    }
    asm volatile("" : "+v"(bZ), "+v"(bR), "+v"(bH), "+v"(bI));

    if (lane < 32) out[(((long)(dir ? Tsz - 1 : 0)) * Bsz + b) * 32 + c] = 0.f;

#define XADDR(s) (((long)(dir ? (Tsz - 2 - (s)) : (1 + (s))) * Bsz + b) * 32 + c)
    long rb = XADDR(0);
    long stride = (long)(dir ? -1 : 1) * Bsz * 32;

    // 4-slot x pipeline: loads issued 4 steps ahead of use (L3-latency safe)
    float l0 = L0[XADDR(0)], r0 = R0[XADDR(0)];
    float l1 = L0[XADDR(1)], r1 = R0[XADDR(1)];
    float l2 = L0[XADDR(2)], r2 = R0[XADDR(2)];
    float l3 = L0[XADDR(3)], r3 = R0[XADDR(3)];
    float h = 0.f;

#define XSTEP(XL, XR, SNEXT)                                                   \
    {                                                                          \
        float x = XL + XR;                                                     \
        float xa = x, xb = x;                                                  \
        plswap16_f(xa, xb);                                                    \
        float xs = selA ? xa : xb;                                             \
        float xk[16];                                                          \
        BCAST16F(xk, xs);                                                      \
        float ha = h, hb = h;                                                  \
        plswap16_f(ha, hb);                                                    \
        float hs = selA ? ha : hb;                                             \
        float hk[16];                                                          \
        BCAST16F(hk, hs);                                                      \
        float az = bZ, ar = bR, ah = bH, ai = bI;                              \
        _Pragma("unroll")                                                      \
        for (int n = 0; n < 16; ++n) {                                         \
            az = fmaf(xk[n], w0[n], az);                                       \
            ar = fmaf(xk[n], w1[n], ar);                                       \
            ai = fmaf(xk[n], w2[n], ai);                                       \
        }                                                                      \
        _Pragma("unroll")                                                      \
        for (int n = 0; n < 16; ++n) {                                         \
            az = fmaf(hk[n], u0[n], az);                                       \
            ar = fmaf(hk[n], u1[n], ar);                                       \
            ah = fmaf(hk[n], u2[n], ah);                                       \
        }                                                                      \
        az = xhalfsum(az); ar = xhalfsum(ar);                                  \
        ah = xhalfsum(ah); ai = xhalfsum(ai);                                  \
        float z = sigmoid_f(az);                                               \
        float r = sigmoid_f(ar);                                               \
        float hh = fmaxf(0.f, fmaf(r, ah, ai));                                \
        h = hh + z * (h - hh);                                                 \
        if (lane < 32) out[rb] = h;                                            \
        rb += stride;                                                          \
        long a2 = XADDR(SNEXT);                                                \
        XL = L0[a2]; XR = R0[a2];                                              \
    }

    for (int sb = 0; sb < 508; sb += 4) {
        int s7 = sb + 7; if (s7 > 510) s7 = 510;
        XSTEP(l0, r0, (sb + 4));
        XSTEP(l1, r1, (sb + 5));
        XSTEP(l2, r2, (sb + 6));
        XSTEP(l3, r3, s7);
    }
    // tail: steps 508, 509, 510 (refills clamped, dead)
    XSTEP(l0, r0, 510);
    XSTEP(l1, r1, 510);
    XSTEP(l2, r2, 510);
#undef XSTEP
#undef XADDR
}

// ---------------- K5b: fold layer-1 BN into dense-1 weights ----------------
__global__ __launch_bounds__(256) void lspd_fold2(
    const float* __restrict__ part, const float* __restrict__ g1, const float* __restrict__ be1,
    const float* __restrict__ Wd1, const float* __restrict__ bd1,
    float* __restrict__ Wdp, float* __restrict__ bdp)
{
    __shared__ float sc[32], tc[32];
    int tid = threadIdx.x;
    if (tid < 32) {
        float S = 0.f, Q = 0.f;
        for (int p = 0; p < 128; ++p) { S += part[p * 64 + tid]; Q += part[p * 64 + 32 + tid]; }
        const float invN = 1.0f / 262144.0f;
        float m = S * invN;
        float v = Q * invN - m * m;
        float s = g1[tid] * __builtin_amdgcn_rsqf(v + 1e-3f);
        sc[tid] = s; tc[tid] = be1[tid] - s * m;
    }
    __syncthreads();
    for (int idx = tid; idx < 1024; idx += 256) {
        int k = idx >> 5;
        Wdp[idx] = sc[k] * Wd1[idx];
    }
    if (tid < 32) {
        float acc = bd1[tid];
        for (int k = 0; k < 32; ++k) acc = fmaf(tc[k], Wd1[k * 32 + tid], acc);
        bdp[tid] = acc;
    }
}

// ---------------- K6: dense + per-t batch BN + classifier + softmax; one block per t ----------------
__global__ __launch_bounds__(512) void lspd_final(
    const float* __restrict__ L1a, const float* __restrict__ R1a,
    const float* __restrict__ Wdp, const float* __restrict__ bdp,
    const float* __restrict__ dg, const float* __restrict__ db,
    const float* __restrict__ Wf, const float* __restrict__ bfv,
    float* __restrict__ outp)
{
    __shared__ alignas(16) float sW[1024];
    __shared__ float sb[32], sWf[352], sbf[16], sS[32], sT[32];
    __shared__ float redS[8][32], redQ[8][32];
    int tid = threadIdx.x, t = blockIdx.x;
    for (int i = tid; i < 1024; i += 512) sW[i] = Wdp[i];
    if (tid < 32)  sb[tid] = bdp[tid];
    if (tid < 352) sWf[tid] = Wf[tid];
    if (tid < 11)  sbf[tid] = bfv[tid];
    __syncthreads();

    size_t base = ((size_t)t * Bsz + tid) * 32;
    float xv[32];
#pragma unroll
    for (int c2 = 0; c2 < 32; c2 += 4) {
        float4 a = *(const float4*)(L1a + base + c2);
        float4 b = *(const float4*)(R1a + base + c2);
        xv[c2 + 0] = a.x + b.x; xv[c2 + 1] = a.y + b.y;
        xv[c2 + 2] = a.z + b.z; xv[c2 + 3] = a.w + b.w;
    }
    float o[32];
#pragma unroll
    for (int g = 0; g < 32; ++g) o[g] = sb[g];
#pragma unroll
    for (int k = 0; k < 32; ++k) {
        float xk = xv[k];
#pragma unroll
        for (int g4 = 0; g4 < 8; ++g4) {
            float4 w = *(const float4*)(sW + k * 32 + g4 * 4);   // same-address LDS broadcast
            o[g4 * 4 + 0] = fmaf(xk, w.x, o[g4 * 4 + 0]);
            o[g4 * 4 + 1] = fmaf(xk, w.y, o[g4 * 4 + 1]);
            o[g4 * 4 + 2] = fmaf(xk, w.z, o[g4 * 4 + 2]);
            o[g4 * 4 + 3] = fmaf(xk, w.w, o[g4 * 4 + 3]);
        }
    }
#pragma unroll
    for (int g = 0; g < 32; ++g) o[g] = fmaxf(o[g], 0.f);

    // per-(t,channel) stats over batch (within block)
    int wv = tid >> 6, lane = tid & 63;
    for (int g = 0; g < 32; ++g) {
        float s = o[g], q = o[g] * o[g];
        for (int d = 1; d < 64; d <<= 1) {
            s += __shfl_xor(s, d, 64);
            q += __shfl_xor(q, d, 64);
        }
        if (lane == 0) { redS[wv][g] = s; redQ[wv][g] = q; }
    }
    __syncthreads();
    if (tid < 32) {
        float S = 0.f, Q = 0.f;
        for (int w2 = 0; w2 < 8; ++w2) { S += redS[w2][tid]; Q += redQ[w2][tid]; }
        float m = S * (1.0f / 512.0f);
        float v = Q * (1.0f / 512.0f) - m * m;
        float s = dg[tid] * __builtin_amdgcn_rsqf(v + 1e-3f);
        sS[tid] = s; sT[tid] = db[tid] - s * m;
    }
    __syncthreads();

    float lg[11];
#pragma unroll
    for (int n = 0; n < 11; ++n) lg[n] = sbf[n];
#pragma unroll
    for (int g = 0; g < 32; ++g) {
        float no = fmaf(o[g], sS[g], sT[g]);
#pragma unroll
        for (int n = 0; n < 11; ++n) lg[n] = fmaf(no, sWf[g * 11 + n], lg[n]);
    }
    float mx = lg[0];
#pragma unroll
    for (int n = 1; n < 11; ++n) mx = fmaxf(mx, lg[n]);
    float sum = 0.f;
#pragma unroll
    for (int n = 0; n < 11; ++n) { lg[n] = __expf(lg[n] - mx); sum += lg[n]; }
    float inv = __builtin_amdgcn_rcpf(sum);
    float* op = outp + ((size_t)tid * Tsz + t) * 11;
#pragma unroll
    for (int n = 0; n < 11; ++n) op[n] = lg[n] * inv;
}

extern "C" void kernel_launch(void* const* d_in, const int* in_sizes, int n_in,
                              void* d_out, int out_size, void* d_ws, size_t ws_size,
                              hipStream_t stream)
{
    (void)in_sizes; (void)n_in; (void)out_size; (void)ws_size;
    const float* x   = (const float*)d_in[0];
    const float* emb = (const float*)d_in[1];
    const float* Wl  = (const float*)d_in[2];
    const float* Ul  = (const float*)d_in[3];
    const float* bl  = (const float*)d_in[4];
    const float* Wr  = (const float*)d_in[5];
    const float* Ur  = (const float*)d_in[6];
    const float* br  = (const float*)d_in[7];
    const float* bng = (const float*)d_in[8];
    const float* bnb = (const float*)d_in[9];
    const float* Wd  = (const float*)d_in[10];
    const float* bd  = (const float*)d_in[11];
    const float* dg  = (const float*)d_in[12];
    const float* db  = (const float*)d_in[13];
    const float* Wf  = (const float*)d_in[14];
    const float* bf  = (const float*)d_in[15];
    float* out = (float*)d_out;

    float* ws = (float*)d_ws;
    float* L0 = ws;
    float* R0 = L0 + 8388608;
    float* L1 = R0 + 8388608;
    float* R1 = L1 + 8388608;
    float* rest = R1 + 8388608;
    int* idxT   = (int*)rest;            // 262144 ints
    float* tabL = rest + 262144;
    float* tabR = tabL + 12288;
    float* part1 = tabR + 12288;         // 8192
    float* part2 = part1 + 8192;         // 8192
    float* WpL = part2 + 8192;           // 3072
    float* WpR = WpL + 3072;
    float* b4L = WpR + 3072;             // 128
    float* b4R = b4L + 128;
    float* Wdp = b4R + 128;              // 1024
    float* bdp = Wdp + 1024;             // 32

    lspd_argmax<<<65536, 256, 0, stream>>>(x, idxT);
    lspd_tab<<<96, 256, 0, stream>>>(emb, Wl, bl, Wr, br, tabL, tabR);
    lspd_gru0<<<1024, 64, 0, stream>>>(idxT, tabL, tabR, Ul, Ur, bl, br, L0, R0);
    lspd_stats<<<128, 256, 0, stream>>>(L0, R0, part1);
    lspd_fold1<<<1, 256, 0, stream>>>(part1, bng, bnb, Wl, Wr, bl, br, WpL, WpR, b4L, b4R);
    lspd_gru1<<<1024, 64, 0, stream>>>(L0, R0, WpL, WpR, b4L, b4R, Ul + 3072, Ur + 3072, L1, R1);
    lspd_stats<<<128, 256, 0, stream>>>(L1, R1, part2);
    lspd_fold2<<<1, 256, 0, stream>>>(part2, bng + 32, bnb + 32, Wd + 1024, bd + 32, Wdp, bdp);
    lspd_final<<<512, 512, 0, stream>>>(L1, R1, Wdp, bdp, dg + 32, db + 32, Wf, bf, out);
}